// Round 2
// baseline (490.023 us; speedup 1.0000x reference)
//
#include <hip/hip_runtime.h>
#include <limits.h>

#define N_PTS   200000
#define N_EDGES 1600000
#define MEM_SIZE (1 << 27)

__global__ void init_mins(int* __restrict__ min1, int* __restrict__ min2) {
    int n = blockIdx.x * blockDim.x + threadIdx.x;
    if (n < N_PTS) { min1[n] = INT_MAX; min2[n] = INT_MAX; }
}

// Half-edge k in [0, 2*N_EDGES): k < N_EDGES -> src=edges[k].x, dst=edges[k].y;
// else src=edges[k-N_EDGES].y, dst=edges[k-N_EDGES].x. One thread per original
// edge handles both directions with one coalesced 8B read.
__global__ void pass_min1(const int2* __restrict__ edges, int* __restrict__ min1) {
    int i = blockIdx.x * blockDim.x + threadIdx.x;
    if (i >= N_EDGES) return;
    int2 e = edges[i];
    atomicMin(&min1[e.x], i);
    atomicMin(&min1[e.y], i + N_EDGES);
}

__global__ void pass_min2(const int2* __restrict__ edges,
                          const int* __restrict__ min1, int* __restrict__ min2) {
    int i = blockIdx.x * blockDim.x + threadIdx.x;
    if (i >= N_EDGES) return;
    int2 e = edges[i];
    if (i != min1[e.x]) atomicMin(&min2[e.x], i);
    int k2 = i + N_EDGES;
    if (k2 != min1[e.y]) atomicMin(&min2[e.y], k2);
}

__device__ __forceinline__ int quant6(float d) {
    // match jnp: clip(round((d/1.0 + 1.0)/2.0 * 63), 0, 63); jnp.round = half-to-even -> rintf
    float x = ((d + 1.0f) / 2.0f) * 63.0f;
    float r = rintf(x);
    r = fminf(fmaxf(r, 0.0f), 63.0f);
    return (int)r;
}

__global__ void finalize(const float* __restrict__ pts, const float* __restrict__ tex,
                         const int2* __restrict__ edges,
                         const int* __restrict__ min1, const int* __restrict__ min2,
                         float* __restrict__ out) {
    int n = blockIdx.x * blockDim.x + threadIdx.x;
    if (n >= N_PTS) return;

    float px = pts[2 * n], py = pts[2 * n + 1];
    int t = (tex[n] > 0.7f) ? 1 : 0;

    int v0x = 0, v0y = 0, t0 = 0, v1x = 0, v1y = 0, t1 = 0;

    int k = min1[n];
    if (k != INT_MAX) {
        int2 e = edges[(k < N_EDGES) ? k : (k - N_EDGES)];
        int dst = (k < N_EDGES) ? e.y : e.x;
        float dx = pts[2 * dst] - px;
        float dy = pts[2 * dst + 1] - py;
        v0x = quant6(dx); v0y = quant6(dy);
        t0 = (tex[dst] > 0.7f) ? 1 : 0;
    }
    k = min2[n];
    if (k != INT_MAX) {
        int2 e = edges[(k < N_EDGES) ? k : (k - N_EDGES)];
        int dst = (k < N_EDGES) ? e.y : e.x;
        float dx = pts[2 * dst] - px;
        float dy = pts[2 * dst + 1] - py;
        v1x = quant6(dx); v1y = quant6(dy);
        t1 = (tex[dst] > 0.7f) ? 1 : 0;
    }

    // hash keeps only cols 0..4 (col4 masked to 3 bits); each rel-variant
    // appears 6 times in rel_all (2 builds x 3 identity-rolls / 3 swap-rolls).
    int h_id = t | (v0x << 6) | (v0y << 12) | (t0 << 18) | ((v1x & 7) << 24);
    int h_sw = t | (v1x << 6) | (v1y << 12) | (t1 << 18) | ((v0x & 7) << 24);

    atomicAdd(&out[h_id], 6.0f);
    atomicAdd(&out[h_sw], 6.0f);
}

extern "C" void kernel_launch(void* const* d_in, const int* in_sizes, int n_in,
                              void* d_out, int out_size, void* d_ws, size_t ws_size,
                              hipStream_t stream) {
    const float* pts   = (const float*)d_in[0];
    const float* tex   = (const float*)d_in[1];
    const int2*  edges = (const int2*)d_in[2];   // int64 in ref -> int32 on device
    const float* mem   = (const float*)d_in[3];
    float*       out   = (float*)d_out;

    int* min1 = (int*)d_ws;
    int* min2 = min1 + N_PTS;

    const int B = 256;
    init_mins<<<(N_PTS + B - 1) / B, B, 0, stream>>>(min1, min2);
    pass_min1<<<(N_EDGES + B - 1) / B, B, 0, stream>>>(edges, min1);
    pass_min2<<<(N_EDGES + B - 1) / B, B, 0, stream>>>(edges, min1, min2);

    // out = mem (the +histogram lands on top via atomics)
    hipMemcpyAsync(out, mem, (size_t)MEM_SIZE * sizeof(float),
                   hipMemcpyDeviceToDevice, stream);

    finalize<<<(N_PTS + B - 1) / B, B, 0, stream>>>(pts, tex, edges, min1, min2, out);
}

// Round 3
// 457.517 us; speedup vs baseline: 1.0711x; 1.0711x over previous
//
#include <hip/hip_runtime.h>
#include <limits.h>

#define N_PTS   200000
#define N_EDGES 1600000
#define MEM_SIZE (1 << 27)

__global__ void init_mins(int* __restrict__ min1, int* __restrict__ min2) {
    int n = blockIdx.x * blockDim.x + threadIdx.x;
    if (n < N_PTS) { min1[n] = INT_MAX; min2[n] = INT_MAX; }
}

// Half-edge k in [0, 2*N_EDGES): k < N_EDGES -> src=edges[k].x, dst=edges[k].y;
// else src=edges[k-N_EDGES].y, dst=edges[k-N_EDGES].x. One thread per original
// edge handles both directions with one coalesced 8B read.
__global__ void pass_min1(const int2* __restrict__ edges, int* __restrict__ min1) {
    int i = blockIdx.x * blockDim.x + threadIdx.x;
    if (i >= N_EDGES) return;
    int2 e = edges[i];
    atomicMin(&min1[e.x], i);
    atomicMin(&min1[e.y], i + N_EDGES);
}

__global__ void pass_min2(const int2* __restrict__ edges,
                          const int* __restrict__ min1, int* __restrict__ min2) {
    int i = blockIdx.x * blockDim.x + threadIdx.x;
    if (i >= N_EDGES) return;
    int2 e = edges[i];
    if (i != min1[e.x]) atomicMin(&min2[e.x], i);
    int k2 = i + N_EDGES;
    if (k2 != min1[e.y]) atomicMin(&min2[e.y], k2);
}

// out = mem, 16B per lane, fully coalesced. Replaces hipMemcpyAsync (which
// ran ~3x slower than HBM peak inside the captured graph).
__global__ void copy_mem(const float4* __restrict__ src, float4* __restrict__ dst) {
    int idx = blockIdx.x * blockDim.x + threadIdx.x;   // MEM_SIZE/4 = 33,554,432 float4s
    dst[idx] = src[idx];
}

__device__ __forceinline__ int quant6(float d) {
    // match jnp: clip(round((d/1.0 + 1.0)/2.0 * 63), 0, 63); jnp.round = half-to-even -> rintf
    float x = ((d + 1.0f) / 2.0f) * 63.0f;
    float r = rintf(x);
    r = fminf(fmaxf(r, 0.0f), 63.0f);
    return (int)r;
}

__global__ void finalize(const float* __restrict__ pts, const float* __restrict__ tex,
                         const int2* __restrict__ edges,
                         const int* __restrict__ min1, const int* __restrict__ min2,
                         float* __restrict__ out) {
    int n = blockIdx.x * blockDim.x + threadIdx.x;
    if (n >= N_PTS) return;

    float px = pts[2 * n], py = pts[2 * n + 1];
    int t = (tex[n] > 0.7f) ? 1 : 0;

    int v0x = 0, v0y = 0, t0 = 0, v1x = 0, v1y = 0, t1 = 0;

    int k = min1[n];
    if (k != INT_MAX) {
        int2 e = edges[(k < N_EDGES) ? k : (k - N_EDGES)];
        int dst = (k < N_EDGES) ? e.y : e.x;
        float dx = pts[2 * dst] - px;
        float dy = pts[2 * dst + 1] - py;
        v0x = quant6(dx); v0y = quant6(dy);
        t0 = (tex[dst] > 0.7f) ? 1 : 0;
    }
    k = min2[n];
    if (k != INT_MAX) {
        int2 e = edges[(k < N_EDGES) ? k : (k - N_EDGES)];
        int dst = (k < N_EDGES) ? e.y : e.x;
        float dx = pts[2 * dst] - px;
        float dy = pts[2 * dst + 1] - py;
        v1x = quant6(dx); v1y = quant6(dy);
        t1 = (tex[dst] > 0.7f) ? 1 : 0;
    }

    // hash keeps only cols 0..4 (col4 masked to 3 bits); each rel-variant
    // appears 6 times in rel_all (2 builds x 3 identity-rolls / 3 swap-rolls).
    int h_id = t | (v0x << 6) | (v0y << 12) | (t0 << 18) | ((v1x & 7) << 24);
    int h_sw = t | (v1x << 6) | (v1y << 12) | (t1 << 18) | ((v0x & 7) << 24);

    atomicAdd(&out[h_id], 6.0f);
    atomicAdd(&out[h_sw], 6.0f);
}

extern "C" void kernel_launch(void* const* d_in, const int* in_sizes, int n_in,
                              void* d_out, int out_size, void* d_ws, size_t ws_size,
                              hipStream_t stream) {
    const float* pts   = (const float*)d_in[0];
    const float* tex   = (const float*)d_in[1];
    const int2*  edges = (const int2*)d_in[2];   // int64 in ref -> int32 on device
    const float* mem   = (const float*)d_in[3];
    float*       out   = (float*)d_out;

    int* min1 = (int*)d_ws;
    int* min2 = min1 + N_PTS;

    const int B = 256;
    init_mins<<<(N_PTS + B - 1) / B, B, 0, stream>>>(min1, min2);
    pass_min1<<<(N_EDGES + B - 1) / B, B, 0, stream>>>(edges, min1);
    pass_min2<<<(N_EDGES + B - 1) / B, B, 0, stream>>>(edges, min1, min2);

    // out = mem via float4 copy kernel (histogram atomics land on top after)
    const int NVEC = MEM_SIZE / 4;               // 33,554,432
    copy_mem<<<NVEC / B, B, 0, stream>>>((const float4*)mem, (float4*)out);

    finalize<<<(N_PTS + B - 1) / B, B, 0, stream>>>(pts, tex, edges, min1, min2, out);
}

// Round 4
// 319.466 us; speedup vs baseline: 1.5339x; 1.4321x over previous
//
#include <hip/hip_runtime.h>
#include <limits.h>

#define N_PTS   200000
#define N_EDGES 1600000
#define MEM_SIZE (1 << 27)

#define EDGE_BLOCKS  (N_EDGES / 256)          // 6250
#define COPY_BLOCKS  32768                    // 33,554,432 float4 / (256 thr * 4 per thr)
#define F4_PER_BLOCK 1024

// pair[n] = (min2 << 32) | min1, both unsigned half-edge indices, min1 <= min2.
// Sentinel: anything >= 2*N_EDGES is "absent".
__global__ void init_pairs(unsigned long long* __restrict__ pair) {
    int n = blockIdx.x * blockDim.x + threadIdx.x;
    if (n < N_PTS) pair[n] = 0xFFFFFFFFFFFFFFFFULL;
}

__device__ __forceinline__ void insert_pair(unsigned long long* p, unsigned int i) {
    // Fast-path plain load: values only decrease, so a stale (older) value is
    // >= truth -> skipping only when i >= stale m2 is conservative & correct.
    unsigned long long old = *(volatile unsigned long long*)p;
    while (true) {
        unsigned int m1 = (unsigned int)(old & 0xFFFFFFFFu);
        unsigned int m2 = (unsigned int)(old >> 32);
        if (i >= m2) return;                              // no change
        unsigned long long nv = (i < m1)
            ? (((unsigned long long)m1 << 32) | i)        // (i, m1)
            : (((unsigned long long)i  << 32) | m1);      // (m1, i)
        unsigned long long prev = atomicCAS(p, old, nv);
        if (prev == old) return;
        old = prev;
    }
}

// Edge blocks first (latency-bound CAS work hides under the HBM-bound copy
// running on the remaining CUs), then copy blocks: 4 float4 per thread.
__global__ void fused_copy_edges(const float4* __restrict__ src, float4* __restrict__ dst,
                                 const int2* __restrict__ edges,
                                 unsigned long long* __restrict__ pair) {
    int b = blockIdx.x;
    if (b < EDGE_BLOCKS) {
        int i = b * 256 + threadIdx.x;                    // one original edge
        int2 e = edges[i];
        insert_pair(&pair[e.x], (unsigned int)i);             // forward half-edge
        insert_pair(&pair[e.y], (unsigned int)(i + N_EDGES)); // reverse half-edge
    } else {
        int cb = b - EDGE_BLOCKS;
        int base = cb * F4_PER_BLOCK + threadIdx.x;
        #pragma unroll
        for (int r = 0; r < 4; ++r)
            dst[base + r * 256] = src[base + r * 256];
    }
}

__device__ __forceinline__ int quant6(float d) {
    // match jnp: clip(round((d + 1)/2 * 63), 0, 63); jnp.round = half-to-even -> rintf
    float x = ((d + 1.0f) / 2.0f) * 63.0f;
    float r = rintf(x);
    r = fminf(fmaxf(r, 0.0f), 63.0f);
    return (int)r;
}

__global__ void finalize(const float* __restrict__ pts, const float* __restrict__ tex,
                         const int2* __restrict__ edges,
                         const unsigned long long* __restrict__ pair,
                         float* __restrict__ out) {
    int n = blockIdx.x * blockDim.x + threadIdx.x;
    if (n >= N_PTS) return;

    float px = pts[2 * n], py = pts[2 * n + 1];
    int t = (tex[n] > 0.7f) ? 1 : 0;

    unsigned long long pr = pair[n];
    unsigned int k1 = (unsigned int)(pr & 0xFFFFFFFFu);
    unsigned int k2 = (unsigned int)(pr >> 32);

    int v0x = 0, v0y = 0, t0 = 0, v1x = 0, v1y = 0, t1 = 0;

    if (k1 < 2u * N_EDGES) {
        int k = (int)k1;
        int2 e = edges[(k < N_EDGES) ? k : (k - N_EDGES)];
        int dst = (k < N_EDGES) ? e.y : e.x;
        v0x = quant6(pts[2 * dst] - px);
        v0y = quant6(pts[2 * dst + 1] - py);
        t0 = (tex[dst] > 0.7f) ? 1 : 0;
    }
    if (k2 < 2u * N_EDGES) {
        int k = (int)k2;
        int2 e = edges[(k < N_EDGES) ? k : (k - N_EDGES)];
        int dst = (k < N_EDGES) ? e.y : e.x;
        v1x = quant6(pts[2 * dst] - px);
        v1y = quant6(pts[2 * dst + 1] - py);
        t1 = (tex[dst] > 0.7f) ? 1 : 0;
    }

    // hash keeps only cols 0..4 (col4 masked to 3 bits); each rel-variant
    // appears 6 times in rel_all (2 builds x 3 identity-rolls / 3 swap-rolls).
    int h_id = t | (v0x << 6) | (v0y << 12) | (t0 << 18) | ((v1x & 7) << 24);
    int h_sw = t | (v1x << 6) | (v1y << 12) | (t1 << 18) | ((v0x & 7) << 24);

    atomicAdd(&out[h_id], 6.0f);
    atomicAdd(&out[h_sw], 6.0f);
}

extern "C" void kernel_launch(void* const* d_in, const int* in_sizes, int n_in,
                              void* d_out, int out_size, void* d_ws, size_t ws_size,
                              hipStream_t stream) {
    const float* pts   = (const float*)d_in[0];
    const float* tex   = (const float*)d_in[1];
    const int2*  edges = (const int2*)d_in[2];   // int64 in ref -> int32 on device
    const float* mem   = (const float*)d_in[3];
    float*       out   = (float*)d_out;

    unsigned long long* pair = (unsigned long long*)d_ws;

    const int B = 256;
    init_pairs<<<(N_PTS + B - 1) / B, B, 0, stream>>>(pair);
    fused_copy_edges<<<EDGE_BLOCKS + COPY_BLOCKS, B, 0, stream>>>(
        (const float4*)mem, (float4*)out, edges, pair);
    finalize<<<(N_PTS + B - 1) / B, B, 0, stream>>>(pts, tex, edges, pair, out);
}

// Round 5
// 287.948 us; speedup vs baseline: 1.7018x; 1.1095x over previous
//
#include <hip/hip_runtime.h>
#include <limits.h>

#define N_PTS   200000
#define N_EDGES 1600000
#define MEM_SIZE (1 << 27)

#define COPY_BLOCKS  32768                    // 33,554,432 float4 / (256 thr * 4 per thr)
#define F4_PER_BLOCK 1024
#define EPB ((N_EDGES + COPY_BLOCKS - 1) / COPY_BLOCKS)   // 49 edges per block

// pair[n] = (min2 << 32) | min1, both unsigned half-edge indices, min1 <= min2.
// Sentinel: anything >= 2*N_EDGES is "absent".
__global__ void init_pairs(unsigned long long* __restrict__ pair) {
    int n = blockIdx.x * blockDim.x + threadIdx.x;
    if (n < N_PTS) pair[n] = 0xFFFFFFFFFFFFFFFFULL;
}

__device__ __forceinline__ void insert_pair(unsigned long long* p, unsigned int i) {
    // Fast-path plain load: pair values only decrease, so a stale (older) value
    // is >= truth -> skipping when i >= stale m2 is conservative & correct.
    unsigned long long old = *(volatile unsigned long long*)p;
    while (true) {
        unsigned int m1 = (unsigned int)(old & 0xFFFFFFFFu);
        unsigned int m2 = (unsigned int)(old >> 32);
        if (i >= m2) return;                              // no change
        unsigned long long nv = (i < m1)
            ? (((unsigned long long)m1 << 32) | i)        // (i, m1)
            : (((unsigned long long)i  << 32) | m1);      // (m1, i)
        unsigned long long prev = atomicCAS(p, old, nv);
        if (prev == old) return;
        old = prev;
    }
}

// Copy + edge CAS interleaved WITHIN every block: copy loads issue first
// (HBM-bound), the ~49 edge lanes' CAS latency hides under them, stores last.
__global__ void fused_copy_edges(const float4* __restrict__ src, float4* __restrict__ dst,
                                 const int2* __restrict__ edges,
                                 unsigned long long* __restrict__ pair) {
    int b = blockIdx.x;
    int t = threadIdx.x;
    int base = b * F4_PER_BLOCK + t;

    float4 v0 = src[base];
    float4 v1 = src[base + 256];
    float4 v2 = src[base + 512];
    float4 v3 = src[base + 768];

    if (t < EPB) {
        int i = b * EPB + t;
        if (i < N_EDGES) {
            int2 e = edges[i];
            insert_pair(&pair[e.x], (unsigned int)i);             // forward half-edge
            insert_pair(&pair[e.y], (unsigned int)(i + N_EDGES)); // reverse half-edge
        }
    }

    dst[base]       = v0;
    dst[base + 256] = v1;
    dst[base + 512] = v2;
    dst[base + 768] = v3;
}

__device__ __forceinline__ int quant6(float d) {
    // match jnp: clip(round((d + 1)/2 * 63), 0, 63); jnp.round = half-to-even -> rintf
    float x = ((d + 1.0f) / 2.0f) * 63.0f;
    float r = rintf(x);
    r = fminf(fmaxf(r, 0.0f), 63.0f);
    return (int)r;
}

__global__ void finalize(const float* __restrict__ pts, const float* __restrict__ tex,
                         const int2* __restrict__ edges,
                         const unsigned long long* __restrict__ pair,
                         float* __restrict__ out) {
    int n = blockIdx.x * blockDim.x + threadIdx.x;
    if (n >= N_PTS) return;

    float px = pts[2 * n], py = pts[2 * n + 1];
    int t = (tex[n] > 0.7f) ? 1 : 0;

    unsigned long long pr = pair[n];
    unsigned int k1 = (unsigned int)(pr & 0xFFFFFFFFu);
    unsigned int k2 = (unsigned int)(pr >> 32);

    int v0x = 0, v0y = 0, t0 = 0, v1x = 0, v1y = 0, t1 = 0;

    if (k1 < 2u * N_EDGES) {
        int k = (int)k1;
        int2 e = edges[(k < N_EDGES) ? k : (k - N_EDGES)];
        int dst = (k < N_EDGES) ? e.y : e.x;
        v0x = quant6(pts[2 * dst] - px);
        v0y = quant6(pts[2 * dst + 1] - py);
        t0 = (tex[dst] > 0.7f) ? 1 : 0;
    }
    if (k2 < 2u * N_EDGES) {
        int k = (int)k2;
        int2 e = edges[(k < N_EDGES) ? k : (k - N_EDGES)];
        int dst = (k < N_EDGES) ? e.y : e.x;
        v1x = quant6(pts[2 * dst] - px);
        v1y = quant6(pts[2 * dst + 1] - py);
        t1 = (tex[dst] > 0.7f) ? 1 : 0;
    }

    // hash keeps only cols 0..4 (col4 masked to 3 bits); each rel-variant
    // appears 6 times in rel_all (2 builds x 3 identity-rolls / 3 swap-rolls).
    int h_id = t | (v0x << 6) | (v0y << 12) | (t0 << 18) | ((v1x & 7) << 24);
    int h_sw = t | (v1x << 6) | (v1y << 12) | (t1 << 18) | ((v0x & 7) << 24);

    atomicAdd(&out[h_id], 6.0f);
    atomicAdd(&out[h_sw], 6.0f);
}

extern "C" void kernel_launch(void* const* d_in, const int* in_sizes, int n_in,
                              void* d_out, int out_size, void* d_ws, size_t ws_size,
                              hipStream_t stream) {
    const float* pts   = (const float*)d_in[0];
    const float* tex   = (const float*)d_in[1];
    const int2*  edges = (const int2*)d_in[2];   // int64 in ref -> int32 on device
    const float* mem   = (const float*)d_in[3];
    float*       out   = (float*)d_out;

    unsigned long long* pair = (unsigned long long*)d_ws;

    const int B = 256;
    init_pairs<<<(N_PTS + B - 1) / B, B, 0, stream>>>(pair);
    fused_copy_edges<<<COPY_BLOCKS, B, 0, stream>>>(
        (const float4*)mem, (float4*)out, edges, pair);
    finalize<<<(N_PTS + B - 1) / B, B, 0, stream>>>(pts, tex, edges, pair, out);
}